// Round 4
// baseline (379.584 us; speedup 1.0000x reference)
//
#include <hip/hip_runtime.h>
#include <math.h>

#define NN 100000
#define NE 1600000
#define D 64

#define BW 512                      // bucket width (pow2, dst>>9)
#define NB 196                      // ceil(NN/BW)
#define P1B 256                     // partition blocks
#define NQ (NE / 4)                 // 400000 int4 quads

// ---------------- P1: per-(block) coarse bucket counts ----------------
__global__ __launch_bounds__(256) void part_count_kernel(const int* __restrict__ src,
                                                         const int* __restrict__ dst,
                                                         int* __restrict__ cntD,
                                                         int* __restrict__ cntS) {
    __shared__ int hD[NB], hS[NB];
    int t = threadIdx.x, b = blockIdx.x;
    for (int i = t; i < NB; i += 256) { hD[i] = 0; hS[i] = 0; }
    __syncthreads();
    const int4* s4 = (const int4*)src;
    const int4* d4 = (const int4*)dst;
    for (int i = b * 256 + t; i < NQ; i += P1B * 256) {
        int4 a = s4[i];
        int4 d = d4[i];
        atomicAdd(&hS[a.x >> 9], 1); atomicAdd(&hS[a.y >> 9], 1);
        atomicAdd(&hS[a.z >> 9], 1); atomicAdd(&hS[a.w >> 9], 1);
        atomicAdd(&hD[d.x >> 9], 1); atomicAdd(&hD[d.y >> 9], 1);
        atomicAdd(&hD[d.z >> 9], 1); atomicAdd(&hD[d.w >> 9], 1);
    }
    __syncthreads();
    for (int i = t; i < NB; i += 256) {
        cntD[i * P1B + b] = hD[i];          // bucket-major, block-minor
        cntS[i * P1B + b] = hS[i];
    }
}

// ---------------- P2: in-place exclusive scan of both count arrays ----------------
__global__ __launch_bounds__(256) void part_scan_kernel(int* __restrict__ cntD,
                                                        int* __restrict__ cntS) {
    __shared__ int part[256];
    int t = threadIdx.x;
    const int CH = NB;                      // 196 elems/thread * 256 = 50176 = NB*P1B
    for (int pass = 0; pass < 2; ++pass) {
        int* a = pass ? cntS : cntD;
        int beg = t * CH;
        int s = 0;
        for (int i = 0; i < CH; ++i) s += a[beg + i];
        part[t] = s;
        __syncthreads();
        for (int o = 1; o < 256; o <<= 1) {
            int u = (t >= o) ? part[t - o] : 0;
            __syncthreads();
            part[t] += u;
            __syncthreads();
        }
        int run = part[t] - s;
        for (int i = 0; i < CH; ++i) { int v = a[beg + i]; a[beg + i] = run; run += v; }
        __syncthreads();
    }
}

// ---------------- P3: partition scatter (LDS cursors only) ----------------
__global__ __launch_bounds__(256) void part_scatter_kernel(const int* __restrict__ src,
                                                           const int* __restrict__ dst,
                                                           const int* __restrict__ offD,
                                                           const int* __restrict__ offS,
                                                           int* __restrict__ psrc,
                                                           int* __restrict__ pdst,
                                                           int* __restrict__ qsrc) {
    __shared__ int curD[NB], curS[NB];
    int t = threadIdx.x, b = blockIdx.x;
    for (int i = t; i < NB; i += 256) {
        curD[i] = offD[i * P1B + b];
        curS[i] = offS[i * P1B + b];
    }
    __syncthreads();
    const int4* s4 = (const int4*)src;
    const int4* d4 = (const int4*)dst;
    for (int i = b * 256 + t; i < NQ; i += P1B * 256) {
        int4 a = s4[i];
        int4 d = d4[i];
        int p;
        p = atomicAdd(&curD[d.x >> 9], 1); psrc[p] = a.x; pdst[p] = d.x;
        p = atomicAdd(&curD[d.y >> 9], 1); psrc[p] = a.y; pdst[p] = d.y;
        p = atomicAdd(&curD[d.z >> 9], 1); psrc[p] = a.z; pdst[p] = d.z;
        p = atomicAdd(&curD[d.w >> 9], 1); psrc[p] = a.w; pdst[p] = d.w;
        p = atomicAdd(&curS[a.x >> 9], 1); qsrc[p] = a.x;
        p = atomicAdd(&curS[a.y >> 9], 1); qsrc[p] = a.y;
        p = atomicAdd(&curS[a.z >> 9], 1); qsrc[p] = a.z;
        p = atomicAdd(&curS[a.w >> 9], 1); qsrc[p] = a.w;
    }
}

// ---------------- P4a: per-bucket src histogram -> nsrc ----------------
__global__ __launch_bounds__(256) void deg_out_kernel(const int* __restrict__ qsrc,
                                                      const int* __restrict__ offS,
                                                      float* __restrict__ nsrc) {
    __shared__ int h[BW];
    int B = blockIdx.x, t = threadIdx.x;
    int beg = offS[B * P1B];
    int end = (B + 1 < NB) ? offS[(B + 1) * P1B] : NE;
    int lo = B << 9;
    for (int i = t; i < BW; i += 256) h[i] = 0;
    __syncthreads();
    for (int i = beg + t; i < end; i += 256) atomicAdd(&h[qsrc[i] - lo], 1);
    __syncthreads();
    for (int i = t; i < BW; i += 256) {
        int n = lo + i;
        if (n < NN) nsrc[n] = 1.0f / sqrtf(fmaxf((float)h[i], 1.0f));
    }
}

// ---------------- P4b: per-bucket dst hist -> row_ptr, ndst, esrc ----------------
__global__ __launch_bounds__(256) void csr_kernel(const int* __restrict__ psrc,
                                                  const int* __restrict__ pdst,
                                                  const int* __restrict__ offD,
                                                  int* __restrict__ row_ptr,
                                                  float* __restrict__ ndst,
                                                  int* __restrict__ esrc) {
    __shared__ int h[BW];
    __shared__ int cur[BW];
    __shared__ int part[256];
    int B = blockIdx.x, t = threadIdx.x;
    int beg = offD[B * P1B];
    int end = (B + 1 < NB) ? offD[(B + 1) * P1B] : NE;
    int lo = B << 9;
    for (int i = t; i < BW; i += 256) h[i] = 0;
    __syncthreads();
    for (int i = beg + t; i < end; i += 256) atomicAdd(&h[pdst[i] - lo], 1);
    __syncthreads();
    // exclusive scan over 512 bins; thread owns bins 2t, 2t+1
    int v0 = h[2 * t], v1 = h[2 * t + 1];
    int s = v0 + v1;
    part[t] = s;
    __syncthreads();
    for (int o = 1; o < 256; o <<= 1) {
        int u = (t >= o) ? part[t - o] : 0;
        __syncthreads();
        part[t] += u;
        __syncthreads();
    }
    int ex = part[t] - s;
    cur[2 * t] = ex;
    cur[2 * t + 1] = ex + v0;
    int n0 = lo + 2 * t, n1 = n0 + 1;
    if (n0 < NN) {
        row_ptr[n0] = beg + ex;
        ndst[n0] = 1.0f / sqrtf(fmaxf((float)v0, 1.0f));
    }
    if (n1 < NN) {
        row_ptr[n1] = beg + ex + v0;
        ndst[n1] = 1.0f / sqrtf(fmaxf((float)v1, 1.0f));
    }
    if (B == NB - 1 && t == 0) row_ptr[NN] = NE;
    __syncthreads();
    for (int i = beg + t; i < end; i += 256) {
        int d = pdst[i] - lo;
        int p = atomicAdd(&cur[d], 1);
        esrc[beg + p] = psrc[i];
    }
}

// ---------------- dense transform: out[v] = nsrc[v] * (xin[v] @ W) ----------------
__global__ __launch_bounds__(256) void transform_kernel(const float* __restrict__ xin,
                                                        const float* __restrict__ W,
                                                        const float* __restrict__ nsrc,
                                                        float* __restrict__ out) {
    __shared__ float Wlds[D * D];
    for (int i = threadIdx.x; i < D * D; i += 256) Wlds[i] = W[i];
    __syncthreads();
    int wave = (blockIdx.x * 256 + threadIdx.x) >> 6;
    int lane = threadIdx.x & 63;
    int g = lane >> 4, c = lane & 15;
    int node0 = wave * 4;
    if (node0 >= NN) return;
    int node = node0 + g;
    float4 xv = *(const float4*)(xin + (size_t)node * D + (c << 2));
    float4 acc = {0.f, 0.f, 0.f, 0.f};
#pragma unroll
    for (int k = 0; k < D; ++k) {
        int srcl = (g << 4) | (k >> 2);
        float comp = ((k & 3) == 0) ? xv.x : ((k & 3) == 1) ? xv.y
                   : ((k & 3) == 2) ? xv.z : xv.w;
        float xk = __shfl(comp, srcl, 64);
        float4 w4 = *(const float4*)(Wlds + k * D + (c << 2));
        acc.x += xk * w4.x; acc.y += xk * w4.y;
        acc.z += xk * w4.z; acc.w += xk * w4.w;
    }
    float sc = nsrc[node];
    acc.x *= sc; acc.y *= sc; acc.z *= sc; acc.w *= sc;
    *(float4*)(out + (size_t)node * D + (c << 2)) = acc;
}

// ---------------- aggregation ----------------
template<int RELU>
__global__ __launch_bounds__(256) void aggregate_kernel(const float* __restrict__ t,
                                                        const int* __restrict__ row_ptr,
                                                        const int* __restrict__ esrc,
                                                        const float* __restrict__ ndst,
                                                        const float* __restrict__ bias,
                                                        float* __restrict__ out) {
    int node = (blockIdx.x * 256 + threadIdx.x) >> 6;
    int lane = threadIdx.x & 63;
    int g = lane >> 4, c = lane & 15;
    if (node >= NN) return;
    int beg = row_ptr[node], end = row_ptr[node + 1];
    float4 a0 = {0.f, 0.f, 0.f, 0.f}, a1 = {0.f, 0.f, 0.f, 0.f};
    int i = beg;
    for (; i + 8 <= end; i += 8) {
        int s0 = esrc[i + g];
        int s1 = esrc[i + 4 + g];
        float4 v0 = *(const float4*)(t + (size_t)s0 * D + (c << 2));
        float4 v1 = *(const float4*)(t + (size_t)s1 * D + (c << 2));
        a0.x += v0.x; a0.y += v0.y; a0.z += v0.z; a0.w += v0.w;
        a1.x += v1.x; a1.y += v1.y; a1.z += v1.z; a1.w += v1.w;
    }
    for (; i < end; i += 4) {
        int e = i + g;
        if (e < end) {
            int s = esrc[e];
            float4 v = *(const float4*)(t + (size_t)s * D + (c << 2));
            a0.x += v.x; a0.y += v.y; a0.z += v.z; a0.w += v.w;
        }
    }
    a0.x += a1.x; a0.y += a1.y; a0.z += a1.z; a0.w += a1.w;
    a0.x += __shfl_xor(a0.x, 16, 64); a0.y += __shfl_xor(a0.y, 16, 64);
    a0.z += __shfl_xor(a0.z, 16, 64); a0.w += __shfl_xor(a0.w, 16, 64);
    a0.x += __shfl_xor(a0.x, 32, 64); a0.y += __shfl_xor(a0.y, 32, 64);
    a0.z += __shfl_xor(a0.z, 32, 64); a0.w += __shfl_xor(a0.w, 32, 64);

    float nd = ndst[node];
    float4 b4 = *(const float4*)(bias + (c << 2));
    float4 h;
    h.x = a0.x * nd + b4.x; h.y = a0.y * nd + b4.y;
    h.z = a0.z * nd + b4.z; h.w = a0.w * nd + b4.w;
    if (RELU) {
        h.x = fmaxf(h.x, 0.f); h.y = fmaxf(h.y, 0.f);
        h.z = fmaxf(h.z, 0.f); h.w = fmaxf(h.w, 0.f);
    }
    if (g == 0) *(float4*)(out + (size_t)node * D + (c << 2)) = h;
}

// ---------------- launcher ----------------
extern "C" void kernel_launch(void* const* d_in, const int* in_sizes, int n_in,
                              void* d_out, int out_size, void* d_ws, size_t ws_size,
                              hipStream_t stream) {
    const float* x  = (const float*)d_in[0];
    const int* src  = (const int*)d_in[1];
    const int* dst  = (const int*)d_in[2];
    const float* W1 = (const float*)d_in[3];
    const float* b1 = (const float*)d_in[4];
    const float* W2 = (const float*)d_in[5];
    const float* b2 = (const float*)d_in[6];
    float* out = (float*)d_out;

    size_t off = 0;
    auto alloc = [&](size_t bytes) -> void* {
        void* p = (char*)d_ws + off;
        off += (bytes + 255) & ~(size_t)255;
        return p;
    };
    int* row_ptr  = (int*)alloc((size_t)(NN + 1) * 4);
    float* nsrc   = (float*)alloc((size_t)NN * 4);
    float* ndst   = (float*)alloc((size_t)NN * 4);
    int* esrc     = (int*)alloc((size_t)NE * 4);                  // 6.4 MB
    float* t_buf  = (float*)alloc((size_t)NN * D * 4);            // 25.6 MB
    float* h1     = (float*)alloc((size_t)NN * D * 4);            // 25.6 MB
    (void)ws_size;

    // preprocessing scratch aliases t_buf (dead until transform1):
    // psrc 6.4 | pdst 6.4 | qsrc 6.4 | cntD/offD 200KB | cntS/offS 200KB = 19.6MB < 25.6MB
    int* psrc = (int*)t_buf;
    int* pdst = psrc + NE;
    int* qsrc = pdst + NE;
    int* cntD = qsrc + NE;
    int* cntS = cntD + NB * P1B;

    const int TB = 256;
    part_count_kernel<<<P1B, TB, 0, stream>>>(src, dst, cntD, cntS);
    part_scan_kernel<<<1, TB, 0, stream>>>(cntD, cntS);
    part_scatter_kernel<<<P1B, TB, 0, stream>>>(src, dst, cntD, cntS, psrc, pdst, qsrc);
    deg_out_kernel<<<NB, TB, 0, stream>>>(qsrc, cntS, nsrc);
    csr_kernel<<<NB, TB, 0, stream>>>(psrc, pdst, cntD, row_ptr, ndst, esrc);

    int tf_blocks = NN / 16;
    int ag_blocks = NN / 4;
    transform_kernel<<<tf_blocks, TB, 0, stream>>>(x, W1, nsrc, t_buf);
    aggregate_kernel<1><<<ag_blocks, TB, 0, stream>>>(t_buf, row_ptr, esrc, ndst, b1, h1);
    transform_kernel<<<tf_blocks, TB, 0, stream>>>(h1, W2, nsrc, t_buf);
    aggregate_kernel<0><<<ag_blocks, TB, 0, stream>>>(t_buf, row_ptr, esrc, ndst, b2, out);
}

// Round 5
// 300.059 us; speedup vs baseline: 1.2650x; 1.2650x over previous
//
#include <hip/hip_runtime.h>
#include <math.h>

#define NN 100000
#define NE 1600000
#define D 64

#define BW 512                      // coarse bucket width (dst>>9)
#define NB 196                      // ceil(NN/BW)
#define P1B 256                     // partition blocks
#define NQ (NE / 4)                 // int4 quads
#define L (NB * P1B)                // 50176 count entries per array
#define SCB 49                      // 49 * 1024 == 50176

typedef _Float16 h4v __attribute__((ext_vector_type(4)));
typedef _Float16 h8v __attribute__((ext_vector_type(8)));

// ---------------- P1: per-block coarse bucket counts ----------------
__global__ __launch_bounds__(256) void part_count_kernel(const int* __restrict__ src,
                                                         const int* __restrict__ dst,
                                                         int* __restrict__ cntD,
                                                         int* __restrict__ cntS) {
    __shared__ int hD[NB], hS[NB];
    int t = threadIdx.x, b = blockIdx.x;
    for (int i = t; i < NB; i += 256) { hD[i] = 0; hS[i] = 0; }
    __syncthreads();
    const int4* s4 = (const int4*)src;
    const int4* d4 = (const int4*)dst;
    for (int i = b * 256 + t; i < NQ; i += P1B * 256) {
        int4 a = s4[i];
        int4 d = d4[i];
        atomicAdd(&hS[a.x >> 9], 1); atomicAdd(&hS[a.y >> 9], 1);
        atomicAdd(&hS[a.z >> 9], 1); atomicAdd(&hS[a.w >> 9], 1);
        atomicAdd(&hD[d.x >> 9], 1); atomicAdd(&hD[d.y >> 9], 1);
        atomicAdd(&hD[d.z >> 9], 1); atomicAdd(&hD[d.w >> 9], 1);
    }
    __syncthreads();
    for (int i = t; i < NB; i += 256) {
        cntD[i * P1B + b] = hD[i];          // bucket-major, block-minor
        cntS[i * P1B + b] = hS[i];
    }
}

// ---------------- P2: 3-phase parallel exclusive scan of cntD and cntS ----------------
__global__ __launch_bounds__(256) void scan_reduce2(const int* __restrict__ cntD,
                                                    const int* __restrict__ cntS,
                                                    int* __restrict__ blocksum) {
    __shared__ int red[256];
    int b = blockIdx.x, t = threadIdx.x;
    const int* a = (b < SCB) ? cntD : cntS;
    int base = (b % SCB) * 1024 + t * 4;
    int4 v = *(const int4*)(a + base);
    red[t] = v.x + v.y + v.z + v.w;
    __syncthreads();
    for (int o = 128; o > 0; o >>= 1) { if (t < o) red[t] += red[t + o]; __syncthreads(); }
    if (t == 0) blocksum[b] = red[0];
}

__global__ void scan_mid(int* __restrict__ blocksum) {
    int t = threadIdx.x;
    if (t < 2) {
        int run = 0;
        for (int i = t * SCB; i < t * SCB + SCB; ++i) {
            int v = blocksum[i]; blocksum[i] = run; run += v;
        }
    }
}

__global__ __launch_bounds__(256) void scan_final2(int* __restrict__ cntD,
                                                   int* __restrict__ cntS,
                                                   const int* __restrict__ blocksum) {
    __shared__ int wsum[4];
    int b = blockIdx.x, t = threadIdx.x;
    int lane = t & 63, w = t >> 6;
    int* a = (b < SCB) ? cntD : cntS;
    int base = (b % SCB) * 1024 + t * 4;
    int4 v = *(const int4*)(a + base);
    int tsum = v.x + v.y + v.z + v.w;
    int incl = tsum;
    for (int o = 1; o < 64; o <<= 1) {
        int u = __shfl_up(incl, o, 64);
        if (lane >= o) incl += u;
    }
    int texcl = incl - tsum;
    if (lane == 63) wsum[w] = incl;
    __syncthreads();
    if (t == 0) { int run = 0; for (int i = 0; i < 4; ++i) { int x = wsum[i]; wsum[i] = run; run += x; } }
    __syncthreads();
    int p0 = blocksum[b] + wsum[w] + texcl;
    int4 o4; o4.x = p0; o4.y = p0 + v.x; o4.z = o4.y + v.y; o4.w = o4.z + v.z;
    *(int4*)(a + base) = o4;
}

// ---------------- P3: partition scatter, packed payloads ----------------
// pbuf = (dst_local_9b << 17) | src_17b ; qloc = src_local_9b
__global__ __launch_bounds__(256) void part_scatter_kernel(const int* __restrict__ src,
                                                           const int* __restrict__ dst,
                                                           const int* __restrict__ offD,
                                                           const int* __restrict__ offS,
                                                           int* __restrict__ pbuf,
                                                           int* __restrict__ qloc) {
    __shared__ int curD[NB], curS[NB];
    int t = threadIdx.x, b = blockIdx.x;
    for (int i = t; i < NB; i += 256) {
        curD[i] = offD[i * P1B + b];
        curS[i] = offS[i * P1B + b];
    }
    __syncthreads();
    const int4* s4 = (const int4*)src;
    const int4* d4 = (const int4*)dst;
    for (int i = b * 256 + t; i < NQ; i += P1B * 256) {
        int4 a = s4[i];
        int4 d = d4[i];
        int p;
        p = atomicAdd(&curD[d.x >> 9], 1); pbuf[p] = ((d.x & 511) << 17) | a.x;
        p = atomicAdd(&curD[d.y >> 9], 1); pbuf[p] = ((d.y & 511) << 17) | a.y;
        p = atomicAdd(&curD[d.z >> 9], 1); pbuf[p] = ((d.z & 511) << 17) | a.z;
        p = atomicAdd(&curD[d.w >> 9], 1); pbuf[p] = ((d.w & 511) << 17) | a.w;
        p = atomicAdd(&curS[a.x >> 9], 1); qloc[p] = a.x & 511;
        p = atomicAdd(&curS[a.y >> 9], 1); qloc[p] = a.y & 511;
        p = atomicAdd(&curS[a.z >> 9], 1); qloc[p] = a.z & 511;
        p = atomicAdd(&curS[a.w >> 9], 1); qloc[p] = a.w & 511;
    }
}

// ---------------- P4a: per-bucket src histogram -> nsrc ----------------
__global__ __launch_bounds__(256) void deg_out_kernel(const int* __restrict__ qloc,
                                                      const int* __restrict__ offS,
                                                      float* __restrict__ nsrc) {
    __shared__ int h[BW];
    int B = blockIdx.x, t = threadIdx.x;
    int beg = offS[B * P1B];
    int end = (B + 1 < NB) ? offS[(B + 1) * P1B] : NE;
    int lo = B << 9;
    for (int i = t; i < BW; i += 256) h[i] = 0;
    __syncthreads();
    for (int i = beg + t; i < end; i += 256) atomicAdd(&h[qloc[i]], 1);
    __syncthreads();
    for (int i = t; i < BW; i += 256) {
        int n = lo + i;
        if (n < NN) nsrc[n] = 1.0f / sqrtf(fmaxf((float)h[i], 1.0f));
    }
}

// ---------------- P4b: per-bucket dst hist -> row_ptr, ndst, esrc ----------------
__global__ __launch_bounds__(256) void csr_kernel(const int* __restrict__ pbuf,
                                                  const int* __restrict__ offD,
                                                  int* __restrict__ row_ptr,
                                                  float* __restrict__ ndst,
                                                  int* __restrict__ esrc) {
    __shared__ int h[BW];
    __shared__ int cur[BW];
    __shared__ int part[256];
    int B = blockIdx.x, t = threadIdx.x;
    int beg = offD[B * P1B];
    int end = (B + 1 < NB) ? offD[(B + 1) * P1B] : NE;
    int lo = B << 9;
    for (int i = t; i < BW; i += 256) h[i] = 0;
    __syncthreads();
    for (int i = beg + t; i < end; i += 256) atomicAdd(&h[pbuf[i] >> 17], 1);
    __syncthreads();
    int v0 = h[2 * t], v1 = h[2 * t + 1];
    int s = v0 + v1;
    part[t] = s;
    __syncthreads();
    for (int o = 1; o < 256; o <<= 1) {
        int u = (t >= o) ? part[t - o] : 0;
        __syncthreads();
        part[t] += u;
        __syncthreads();
    }
    int ex = part[t] - s;
    cur[2 * t] = ex;
    cur[2 * t + 1] = ex + v0;
    int n0 = lo + 2 * t, n1 = n0 + 1;
    if (n0 < NN) {
        row_ptr[n0] = beg + ex;
        ndst[n0] = 1.0f / sqrtf(fmaxf((float)v0, 1.0f));
    }
    if (n1 < NN) {
        row_ptr[n1] = beg + ex + v0;
        ndst[n1] = 1.0f / sqrtf(fmaxf((float)v1, 1.0f));
    }
    if (B == NB - 1 && t == 0) row_ptr[NN] = NE;
    __syncthreads();
    for (int i = beg + t; i < end; i += 256) {
        int v = pbuf[i];
        int p = atomicAdd(&cur[v >> 17], 1);
        esrc[beg + p] = v & 0x1FFFF;
    }
}

// ---------------- dense transform: t[v] = fp16( nsrc[v] * (xin[v] @ W) ) ----------------
__global__ __launch_bounds__(256) void transform_kernel(const float* __restrict__ xin,
                                                        const float* __restrict__ W,
                                                        const float* __restrict__ nsrc,
                                                        _Float16* __restrict__ out) {
    __shared__ float Wlds[D * D];
    for (int i = threadIdx.x; i < D * D; i += 256) Wlds[i] = W[i];
    __syncthreads();
    int wave = (blockIdx.x * 256 + threadIdx.x) >> 6;
    int lane = threadIdx.x & 63;
    int g = lane >> 4, c = lane & 15;
    int node0 = wave * 4;
    if (node0 >= NN) return;
    int node = node0 + g;
    float4 xv = *(const float4*)(xin + (size_t)node * D + (c << 2));
    float4 acc = {0.f, 0.f, 0.f, 0.f};
#pragma unroll
    for (int k = 0; k < D; ++k) {
        int srcl = (g << 4) | (k >> 2);
        float comp = ((k & 3) == 0) ? xv.x : ((k & 3) == 1) ? xv.y
                   : ((k & 3) == 2) ? xv.z : xv.w;
        float xk = __shfl(comp, srcl, 64);
        float4 w4 = *(const float4*)(Wlds + k * D + (c << 2));
        acc.x += xk * w4.x; acc.y += xk * w4.y;
        acc.z += xk * w4.z; acc.w += xk * w4.w;
    }
    float sc = nsrc[node];
    h4v o;
    o[0] = (_Float16)(acc.x * sc); o[1] = (_Float16)(acc.y * sc);
    o[2] = (_Float16)(acc.z * sc); o[3] = (_Float16)(acc.w * sc);
    *(h4v*)(out + (size_t)node * D + (c << 2)) = o;
}

// ---------------- aggregation (fp16 gather, fp32 accumulate) ----------------
// wave per node: lane = (g = edge-slot [0..7], c = col-oct [0..7]); 16B/lane loads.
template<int RELU>
__global__ __launch_bounds__(256) void aggregate_kernel(const _Float16* __restrict__ t,
                                                        const int* __restrict__ row_ptr,
                                                        const int* __restrict__ esrc,
                                                        const float* __restrict__ ndst,
                                                        const float* __restrict__ bias,
                                                        float* __restrict__ out) {
    int node = (blockIdx.x * 256 + threadIdx.x) >> 6;
    int lane = threadIdx.x & 63;
    int g = lane >> 3, c = lane & 7;
    if (node >= NN) return;
    int beg = row_ptr[node], end = row_ptr[node + 1];
    float a0[8] = {0,0,0,0,0,0,0,0};
    float a1[8] = {0,0,0,0,0,0,0,0};
    int i = beg;
    for (; i + 16 <= end; i += 16) {
        int s0 = esrc[i + g];
        int s1 = esrc[i + 8 + g];
        h8v v0 = *(const h8v*)(t + (size_t)s0 * D + (c << 3));
        h8v v1 = *(const h8v*)(t + (size_t)s1 * D + (c << 3));
#pragma unroll
        for (int j = 0; j < 8; ++j) { a0[j] += (float)v0[j]; a1[j] += (float)v1[j]; }
    }
    for (; i < end; i += 8) {
        int e = i + g;
        if (e < end) {
            int s = esrc[e];
            h8v v = *(const h8v*)(t + (size_t)s * D + (c << 3));
#pragma unroll
            for (int j = 0; j < 8; ++j) a0[j] += (float)v[j];
        }
    }
#pragma unroll
    for (int j = 0; j < 8; ++j) a0[j] += a1[j];
    // butterfly over the 8 edge-slot groups (lane bits 3,4,5)
#pragma unroll
    for (int j = 0; j < 8; ++j) {
        a0[j] += __shfl_xor(a0[j], 8, 64);
        a0[j] += __shfl_xor(a0[j], 16, 64);
        a0[j] += __shfl_xor(a0[j], 32, 64);
    }
    float nd = ndst[node];
    float4 blo = *(const float4*)(bias + (c << 3));
    float4 bhi = *(const float4*)(bias + (c << 3) + 4);
    float h[8];
    h[0] = a0[0] * nd + blo.x; h[1] = a0[1] * nd + blo.y;
    h[2] = a0[2] * nd + blo.z; h[3] = a0[3] * nd + blo.w;
    h[4] = a0[4] * nd + bhi.x; h[5] = a0[5] * nd + bhi.y;
    h[6] = a0[6] * nd + bhi.z; h[7] = a0[7] * nd + bhi.w;
    if (RELU) {
#pragma unroll
        for (int j = 0; j < 8; ++j) h[j] = fmaxf(h[j], 0.f);
    }
    if (g == 0) {
        float4 o0 = {h[0], h[1], h[2], h[3]};
        float4 o1 = {h[4], h[5], h[6], h[7]};
        *(float4*)(out + (size_t)node * D + (c << 3)) = o0;
        *(float4*)(out + (size_t)node * D + (c << 3) + 4) = o1;
    }
}

// ---------------- launcher ----------------
extern "C" void kernel_launch(void* const* d_in, const int* in_sizes, int n_in,
                              void* d_out, int out_size, void* d_ws, size_t ws_size,
                              hipStream_t stream) {
    const float* x  = (const float*)d_in[0];
    const int* src  = (const int*)d_in[1];
    const int* dst  = (const int*)d_in[2];
    const float* W1 = (const float*)d_in[3];
    const float* b1 = (const float*)d_in[4];
    const float* W2 = (const float*)d_in[5];
    const float* b2 = (const float*)d_in[6];
    float* out = (float*)d_out;

    size_t off = 0;
    auto alloc = [&](size_t bytes) -> void* {
        void* p = (char*)d_ws + off;
        off += (bytes + 255) & ~(size_t)255;
        return p;
    };
    int* row_ptr    = (int*)alloc((size_t)(NN + 1) * 4);
    float* nsrc     = (float*)alloc((size_t)NN * 4);
    float* ndst     = (float*)alloc((size_t)NN * 4);
    int* blocksum   = (int*)alloc((size_t)2 * SCB * 4);
    int* esrc       = (int*)alloc((size_t)NE * 4);                 // 6.4 MB
    _Float16* t_h   = (_Float16*)alloc((size_t)NN * D * 2);        // 12.8 MB
    float* h1       = (float*)alloc((size_t)NN * D * 4);           // 25.6 MB
    (void)ws_size;

    // preprocessing scratch aliases h1 (dead until aggregate1):
    // pbuf 6.4 | qloc 6.4 | cntD 200KB | cntS 200KB = 13.2MB < 25.6MB
    int* pbuf = (int*)h1;
    int* qloc = pbuf + NE;
    int* cntD = qloc + NE;
    int* cntS = cntD + L;

    const int TB = 256;
    part_count_kernel<<<P1B, TB, 0, stream>>>(src, dst, cntD, cntS);
    scan_reduce2<<<2 * SCB, TB, 0, stream>>>(cntD, cntS, blocksum);
    scan_mid<<<1, 64, 0, stream>>>(blocksum);
    scan_final2<<<2 * SCB, TB, 0, stream>>>(cntD, cntS, blocksum);
    part_scatter_kernel<<<P1B, TB, 0, stream>>>(src, dst, cntD, cntS, pbuf, qloc);
    deg_out_kernel<<<NB, TB, 0, stream>>>(qloc, cntS, nsrc);
    csr_kernel<<<NB, TB, 0, stream>>>(pbuf, cntD, row_ptr, ndst, esrc);

    int tf_blocks = NN / 16;
    int ag_blocks = NN / 4;
    transform_kernel<<<tf_blocks, TB, 0, stream>>>(x, W1, nsrc, t_h);
    aggregate_kernel<1><<<ag_blocks, TB, 0, stream>>>(t_h, row_ptr, esrc, ndst, b1, h1);
    transform_kernel<<<tf_blocks, TB, 0, stream>>>(h1, W2, nsrc, t_h);
    aggregate_kernel<0><<<ag_blocks, TB, 0, stream>>>(t_h, row_ptr, esrc, ndst, b2, out);
}